// Round 3
// baseline (283.476 us; speedup 1.0000x reference)
//
#include <hip/hip_runtime.h>
#include <hip/hip_bf16.h>
#include <cstdint>

// STFT magnitude as fused GEMM, m201-parity wave mapping:
//   out[b,k,t] = sqrt( (basis_r[k,:]·frame)^2 + (basis_i[k,:]·frame)^2 )
// Block tile: 128 bins x 256 frames, BK=64, 8 waves (2 bin-halves x 4 frame-quarters).
// Wave tile: 64 bins x 64 frames, BOTH planes (real+imag) -> 128 A-rows/wave.
// Per K=32: ar[4]+ai[4]+b[4] = 12 ds_read_b128, 32 MFMA (b reused real/imag).
// 4 phases/K-tile: {real-k0, imag-k0, real-k1, imag-k1}, each phase =
//   reads | stage 1 half-tile of t+1 | (vmcnt?) | barrier | setprio+16 MFMA | barrier.
// Stage order B0,B1,A0,A1; vmcnt(2) only at end of ph0 and ph3 (never 0 in loop).
// LDS XOR swizzle granule^(row&7): linear gld_lds dest + pre-swizzled source + swz read.

#define FILT   2048
#define HOP    512
#define CUT    1025
#define NBATCH 32
#define TFR    626
#define NFR    (NBATCH * TFR)      // 20032
#define LSIG   320000

#define BK 64
#define NK (FILT / BK)             // 32 K-tiles
#define BM 128
#define BN 256
#define MT 9
#define NT 79
#define MPAD 1152
#define NPAD (NT * BN)             // 20224
#define NWG (MT * NT)              // 711

typedef __attribute__((ext_vector_type(8))) short short8;
typedef __attribute__((ext_vector_type(4))) float f32x4;

__device__ __forceinline__ short bf16r(float f) {
  __hip_bfloat16 h = __float2bfloat16(f);
  return __builtin_bit_cast(short, h);
}

__device__ __forceinline__ short8 pack8(float4 a, float4 b) {
  short8 v;
  v[0] = bf16r(a.x); v[1] = bf16r(a.y); v[2] = bf16r(a.z); v[3] = bf16r(a.w);
  v[4] = bf16r(b.x); v[5] = bf16r(b.y); v[6] = bf16r(b.z); v[7] = bf16r(b.w);
  return v;
}

__device__ __forceinline__ void gld_lds16(const short* g, short* l) {
  __builtin_amdgcn_global_load_lds(
      (const __attribute__((address_space(1))) uint32_t*)g,
      (__attribute__((address_space(3))) uint32_t*)l, 16, 0, 0);
}

__device__ __forceinline__ void barf() {
  asm volatile("" ::: "memory");
  __builtin_amdgcn_s_barrier();
  asm volatile("" ::: "memory");
}

// -------- stage 1: windowed frames (reflect pad), f32 -> bf16 --------
__global__ void build_frames(const float* __restrict__ x, short* __restrict__ F) {
  const int f = blockIdx.x;                 // 0..NPAD-1
  const size_t base = (size_t)f * FILT;
  const int i = threadIdx.x * 8;            // 256 thr * 8 = 2048
  short8 v;
  if (f >= NFR) {
    v = (short8)(short)0;
  } else {
    const int b = f / TFR, t = f - b * TFR;
    const float* xb = x + (size_t)b * LSIG;
    const int j0 = t * HOP - 1024 + i;
    if (j0 >= 0 && j0 + 8 <= LSIG) {
      float4 a = *(const float4*)(xb + j0);
      float4 c = *(const float4*)(xb + j0 + 4);
      v = pack8(a, c);
    } else {
      #pragma unroll
      for (int e = 0; e < 8; ++e) {
        int j = j0 + e;
        j = j < 0 ? -j : (j >= LSIG ? 2 * LSIG - 2 - j : j);
        v[e] = bf16r(xb[j]);
      }
    }
  }
  *(short8*)&F[base + i] = v;
}

// -------- stage 1b: basis f32 -> bf16, split real/imag, zero-pad rows --------
__global__ void convert_basis(const float* __restrict__ bs, short* __restrict__ A) {
  const int row = blockIdx.x;               // 0..2*MPAD-1
  const int p = row / MPAD;
  const int k = row - p * MPAD;
  const size_t dst = (size_t)row * FILT;
  const int i = threadIdx.x * 8;
  short8 v;
  if (k < CUT) {
    const float* src = bs + (size_t)(p * CUT + k) * FILT + i;
    float4 a = *(const float4*)src;
    float4 c = *(const float4*)(src + 4);
    v = pack8(a, c);
  } else {
    v = (short8)(short)0;
  }
  *(short8*)&A[dst + i] = v;
}

// -------- stage 2: fused GEMM + magnitude, 4-phase counted-vmcnt schedule --------
__global__ __launch_bounds__(512, 2)
void stft_gemm8(const short* __restrict__ Aw, const short* __restrict__ Fw,
                float* __restrict__ out)
{
  __shared__ alignas(16) short sA[2][256][64];   // [buf][plane*128+row][col] 64 KiB
  __shared__ alignas(16) short sB[2][256][64];   // [buf][frame row][col]     64 KiB

  const int tid  = threadIdx.x;
  const int wave = tid >> 6;
  const int lane = tid & 63;
  const int wr = wave >> 2;          // 0..1: 64-bin half
  const int wc = wave & 3;           // 0..3: 64-frame quarter

  // bijective XCD-aware block swizzle (m204)
  int bid = blockIdx.x;
  { const int q = NWG / 8, r = NWG % 8, xc = bid & 7, o = bid >> 3;
    bid = (xc < r ? xc * (q + 1) : r * (q + 1) + (xc - r) * q) + o; }
  const int by = bid / NT, bx = bid - by * NT;
  const int m0 = by * BM, n0 = bx * BN;

  // ---- staging geometry (pre-swizzled global source, linear LDS dest) ----
  const int lrow = lane >> 3;                 // row within 8-row chunk
  const int soff = ((lane & 7) ^ lrow) * 8;   // swizzled source col (shorts)
  const int ch0 = wave * 2, ch1 = wave * 2 + 1;

  const short* aRow0 = Aw + (size_t)(m0 + ch0 * 8 + lrow) * FILT + soff;
  const short* aRow1 = Aw + (size_t)(m0 + ch1 * 8 + lrow) * FILT + soff;
  const short* bRow0 = Fw + (size_t)(n0 + ch0 * 8 + lrow) * FILT + soff;
  const short* bRow1 = Fw + (size_t)(n0 + ch1 * 8 + lrow) * FILT + soff;
  const size_t planeOff = (size_t)MPAD * FILT;
  const size_t halfOff  = (size_t)128 * FILT;

  auto stageA = [&](int p, int bf, int k0) {   // plane p (0=real,1=imag), 128 rows
    gld_lds16(aRow0 + (size_t)p * planeOff + k0, &sA[bf][p * 128 + ch0 * 8][0]);
    gld_lds16(aRow1 + (size_t)p * planeOff + k0, &sA[bf][p * 128 + ch1 * 8][0]);
  };
  auto stageB = [&](int h, int bf, int k0) {   // frame half h, 128 rows
    gld_lds16(bRow0 + (size_t)h * halfOff + k0, &sB[bf][h * 128 + ch0 * 8][0]);
    gld_lds16(bRow1 + (size_t)h * halfOff + k0, &sB[bf][h * 128 + ch1 * 8][0]);
  };

  // ---- frag-read geometry (swizzled ds_read; row&7 == lane&7 for all frags) ----
  const int fr = lane & 15;
  const int l7 = lane & 7;
  const int fg = lane >> 4;                       // 0..3
  const int g0 = (fg ^ l7) * 8;                   // k-half 0 granule (shorts)
  const int g1 = ((4 + fg) ^ l7) * 8;             // k-half 1

  f32x4 acc_r[4][4], acc_i[4][4];
  #pragma unroll
  for (int m = 0; m < 4; ++m)
    #pragma unroll
    for (int n = 0; n < 4; ++n) { acc_r[m][n] = (f32x4)0.f; acc_i[m][n] = (f32x4)0.f; }

  short8 ar[4], ai[4], b[4];

  auto rdAr = [&](int kh, int bf) {
    const int g = kh ? g1 : g0;
    #pragma unroll
    for (int m = 0; m < 4; ++m)
      ar[m] = *(const short8*)&sA[bf][wr * 64 + m * 16 + fr][g];
  };
  auto rdAi = [&](int kh, int bf) {
    const int g = kh ? g1 : g0;
    #pragma unroll
    for (int m = 0; m < 4; ++m)
      ai[m] = *(const short8*)&sA[bf][128 + wr * 64 + m * 16 + fr][g];
  };
  auto rdB = [&](int kh, int bf) {
    const int g = kh ? g1 : g0;
    #pragma unroll
    for (int n = 0; n < 4; ++n)
      b[n] = *(const short8*)&sB[bf][wc * 64 + n * 16 + fr][g];
  };

  auto MMr = [&]() {
    __builtin_amdgcn_s_setprio(1);
    #pragma unroll
    for (int m = 0; m < 4; ++m)
      #pragma unroll
      for (int n = 0; n < 4; ++n)
        acc_r[m][n] = __builtin_amdgcn_mfma_f32_16x16x32_bf16(ar[m], b[n], acc_r[m][n], 0, 0, 0);
    __builtin_amdgcn_s_setprio(0);
  };
  auto MMi = [&]() {
    __builtin_amdgcn_s_setprio(1);
    #pragma unroll
    for (int m = 0; m < 4; ++m)
      #pragma unroll
      for (int n = 0; n < 4; ++n)
        acc_i[m][n] = __builtin_amdgcn_mfma_f32_16x16x32_bf16(ai[m], b[n], acc_i[m][n], 0, 0, 0);
    __builtin_amdgcn_s_setprio(0);
  };

  // ---- prologue: stage tile 0 -> buf 0, order B0,B1,A0,A1; leave A1 in flight ----
  stageB(0, 0, 0);
  stageB(1, 0, 0);
  stageA(0, 0, 0);
  stageA(1, 0, 0);
  asm volatile("s_waitcnt vmcnt(2)" ::: "memory");
  barf();

  #pragma unroll 2
  for (int t = 0; t < NK; ++t) {
    const int b_ = t & 1, bn = b_ ^ 1;
    const int k1 = ((t + 1) & (NK - 1)) * BK;   // wraps on last iter (garbage, drained)

    // ph0: real x k-half0. Needs B0,B1,A0(t) -- ensured by prior vmcnt(2)+barrier.
    rdAr(0, b_); rdB(0, b_);
    stageB(0, bn, k1);
    asm volatile("s_waitcnt vmcnt(2)" ::: "memory");   // drain A1(t); leaves B0(t+1)
    barf();
    MMr();
    barf();

    // ph1: imag x k-half0 (reuse b). Needs A1(t).
    rdAi(0, b_);
    stageB(1, bn, k1);
    barf();
    MMi();
    barf();

    // ph2: real x k-half1. Tile t fully resident already.
    rdAr(1, b_); rdB(1, b_);
    stageA(0, bn, k1);
    barf();
    MMr();
    barf();

    // ph3: imag x k-half1.
    rdAi(1, b_);
    stageA(1, bn, k1);
    asm volatile("s_waitcnt vmcnt(2)" ::: "memory");   // drain B0,B1,A0(t+1)
    barf();
    MMi();
    barf();
  }
  asm volatile("s_waitcnt vmcnt(0)" ::: "memory");

  // ---- epilogue: magnitude, guarded strided write ----
  const int cl = lane & 15;
  const int rg = (lane >> 4) * 4;
  #pragma unroll
  for (int n = 0; n < 4; ++n) {
    const int f = n0 + wc * 64 + n * 16 + cl;
    if (f >= NFR) continue;
    const int bb = f / TFR, tt = f - bb * TFR;
    float* ob = out + (size_t)bb * (CUT * TFR) + tt;
    #pragma unroll
    for (int m = 0; m < 4; ++m) {
      #pragma unroll
      for (int r = 0; r < 4; ++r) {
        const int k = m0 + wr * 64 + m * 16 + rg + r;
        if (k < CUT) {
          float re = acc_r[m][n][r];
          float im = acc_i[m][n][r];
          ob[(size_t)k * TFR] = sqrtf(re * re + im * im);
        }
      }
    }
  }
}

// -------- fallback: reg-staged 128x128 (no ws needed) --------
__global__ __launch_bounds__(256, 2)
void stft_gemm_fb(const float* __restrict__ basis, const float* __restrict__ x,
                  float* __restrict__ out)
{
  __shared__ alignas(16) short sA[2][128][64];
  __shared__ alignas(16) short sB[128][64];

  const int tid  = threadIdx.x;
  const int wave = tid >> 6;
  const int lane = tid & 63;
  const int n0 = blockIdx.x * 128;
  const int m0 = blockIdx.y * 128;

  f32x4 acc_r[4][4], acc_i[4][4];
  #pragma unroll
  for (int i = 0; i < 4; ++i)
    #pragma unroll
    for (int j = 0; j < 4; ++j) { acc_r[i][j] = (f32x4)0.f; acc_i[i][j] = (f32x4)0.f; }

  const int sr = tid >> 1;
  const int sh = (tid & 1) * 32;

  for (int k0 = 0; k0 < FILT; k0 += BK) {
    #pragma unroll
    for (int p = 0; p < 2; ++p) {
      const int k = m0 + sr;
      short8 v[4];
      if (k < CUT) {
        const float* src = basis + (size_t)(p * CUT + k) * FILT + k0 + sh;
        #pragma unroll
        for (int q = 0; q < 4; ++q) {
          float4 a = *(const float4*)(src + q * 8);
          float4 b = *(const float4*)(src + q * 8 + 4);
          v[q] = pack8(a, b);
        }
      } else {
        #pragma unroll
        for (int q = 0; q < 4; ++q) v[q] = (short8)(short)0;
      }
      #pragma unroll
      for (int q = 0; q < 4; ++q) *(short8*)&sA[p][sr][sh + q * 8] = v[q];
    }
    {
      const int f = n0 + sr;
      short8 v[4];
      if (f < NFR) {
        const int b = f / TFR, t = f - b * TFR;
        const float* xb = x + (size_t)b * LSIG;
        const int j0 = t * HOP + k0 + sh - 1024;
        if (j0 >= 0 && j0 + 32 <= LSIG) {
          #pragma unroll
          for (int q = 0; q < 4; ++q) {
            float4 a  = *(const float4*)(xb + j0 + q * 8);
            float4 b2 = *(const float4*)(xb + j0 + q * 8 + 4);
            v[q] = pack8(a, b2);
          }
        } else {
          #pragma unroll
          for (int q = 0; q < 4; ++q)
            #pragma unroll
            for (int e = 0; e < 8; ++e) {
              int j = j0 + q * 8 + e;
              j = j < 0 ? -j : (j >= LSIG ? 2 * LSIG - 2 - j : j);
              v[q][e] = bf16r(xb[j]);
            }
        }
      } else {
        #pragma unroll
        for (int q = 0; q < 4; ++q) v[q] = (short8)(short)0;
      }
      #pragma unroll
      for (int q = 0; q < 4; ++q) *(short8*)&sB[sr][sh + q * 8] = v[q];
    }
    __syncthreads();

    const int ra = lane & 15;
    #pragma unroll
    for (int kk = 0; kk < BK; kk += 32) {
      const int col = kk + (lane >> 4) * 8;
      short8 arr[4], aii[4], bfr[4];
      #pragma unroll
      for (int i = 0; i < 4; ++i) {
        const int rm = (wave >> 1) * 64 + i * 16 + ra;
        arr[i] = *(const short8*)&sA[0][rm][col];
        aii[i] = *(const short8*)&sA[1][rm][col];
        const int rn = (wave & 1) * 64 + i * 16 + ra;
        bfr[i] = *(const short8*)&sB[rn][col];
      }
      #pragma unroll
      for (int i = 0; i < 4; ++i)
        #pragma unroll
        for (int j = 0; j < 4; ++j) {
          acc_r[i][j] = __builtin_amdgcn_mfma_f32_16x16x32_bf16(arr[i], bfr[j], acc_r[i][j], 0, 0, 0);
          acc_i[i][j] = __builtin_amdgcn_mfma_f32_16x16x32_bf16(aii[i], bfr[j], acc_i[i][j], 0, 0, 0);
        }
    }
    __syncthreads();
  }

  const int wm0 = m0 + (wave >> 1) * 64;
  const int wn0 = n0 + (wave & 1) * 64;
  const int cl = lane & 15;
  const int rg = (lane >> 4) * 4;
  #pragma unroll
  for (int j = 0; j < 4; ++j) {
    const int f = wn0 + j * 16 + cl;
    if (f >= NFR) continue;
    const int b = f / TFR, t = f - b * TFR;
    float* ob = out + (size_t)b * (CUT * TFR) + t;
    #pragma unroll
    for (int i = 0; i < 4; ++i) {
      #pragma unroll
      for (int r = 0; r < 4; ++r) {
        const int k = wm0 + i * 16 + rg + r;
        if (k < CUT) {
          float re = acc_r[i][j][r], im = acc_i[i][j][r];
          ob[(size_t)k * TFR] = sqrtf(re * re + im * im);
        }
      }
    }
  }
}

extern "C" void kernel_launch(void* const* d_in, const int* in_sizes, int n_in,
                              void* d_out, int out_size, void* d_ws, size_t ws_size,
                              hipStream_t stream) {
  const float* x     = (const float*)d_in[0];
  const float* basis = (const float*)d_in[1];
  float* out = (float*)d_out;

  const size_t fbytes = (size_t)NPAD * FILT * sizeof(short);       // 82,837,504
  const size_t abytes = (size_t)2 * MPAD * FILT * sizeof(short);   //  9,437,184

  if (ws_size >= fbytes + abytes) {
    short* F = (short*)d_ws;
    short* A = (short*)((char*)d_ws + fbytes);
    build_frames<<<NPAD, 256, 0, stream>>>(x, F);
    convert_basis<<<2 * MPAD, 256, 0, stream>>>(basis, A);
    stft_gemm8<<<NWG, 512, 0, stream>>>(A, F, out);
  } else {
    stft_gemm_fb<<<dim3(157, 9), 256, 0, stream>>>(basis, x, out);
  }
}

// Round 4
// 252.715 us; speedup vs baseline: 1.1217x; 1.1217x over previous
//
#include <hip/hip_runtime.h>
#include <hip/hip_bf16.h>
#include <cstdint>

// STFT magnitude as fused GEMM. Round 4: stage B directly from a bf16
// reflect-padded signal (no materialized frames => per-XCD working set fits L2),
// and give every staged load a uniform 3-phase counted-vmcnt prefetch distance.
//   out[b,k,t] = sqrt( (basis_r[k,:]·frame)^2 + (basis_i[k,:]·frame)^2 )
// Block tile: 128 bins x 256 frames, BK=64, 8 waves; wave tile: 64 bins(x2 planes) x 64 frames.
// Per K-tile (4 phases): ph0 {rd Ar-k0,B-k0 | issue B0,B1,A0(t+1) | vmcnt(6) | bar | 16 MFMA | bar}
//                        ph1 {rd Ai-k0      | issue A1(t+1)       |          | bar | 16 MFMA | bar}
//                        ph2 {rd Ar-k1,B-k1 |                     |          | bar | 16 MFMA | bar}
//                        ph3 {rd Ai-k1      |                     | vmcnt(2) | bar | 16 MFMA | bar}
// Steady invariant at loop top: only A1(t) in flight. Never drains to 0 in loop.
// LDS XOR swizzle granule^(row&7): linear gld_lds dest + pre-swizzled source + swz read.

#define FILT   2048
#define HOP    512
#define CUT    1025
#define NBATCH 32
#define TFR    626
#define NFR    (NBATCH * TFR)      // 20032
#define LSIG   320000
#define LPAD   (LSIG + FILT)       // 322048 padded signal length

#define BK 64
#define NK (FILT / BK)             // 32 K-tiles
#define BM 128
#define BN 256
#define MT 9
#define NT 79
#define MPAD 1152
#define NWG (MT * NT)              // 711

typedef __attribute__((ext_vector_type(8))) short short8;
typedef __attribute__((ext_vector_type(4))) float f32x4;

__device__ __forceinline__ short bf16r(float f) {
  __hip_bfloat16 h = __float2bfloat16(f);
  return __builtin_bit_cast(short, h);
}

__device__ __forceinline__ short8 pack8(float4 a, float4 b) {
  short8 v;
  v[0] = bf16r(a.x); v[1] = bf16r(a.y); v[2] = bf16r(a.z); v[3] = bf16r(a.w);
  v[4] = bf16r(b.x); v[5] = bf16r(b.y); v[6] = bf16r(b.z); v[7] = bf16r(b.w);
  return v;
}

__device__ __forceinline__ void gld_lds16(const short* g, short* l) {
  __builtin_amdgcn_global_load_lds(
      (const __attribute__((address_space(1))) uint32_t*)g,
      (__attribute__((address_space(3))) uint32_t*)l, 16, 0, 0);
}

__device__ __forceinline__ void barf() {
  asm volatile("" ::: "memory");
  __builtin_amdgcn_s_barrier();
  asm volatile("" ::: "memory");
}

// -------- stage 1a: reflect-padded signal, f32 -> bf16 [32][LPAD] --------
__global__ void pad_signal(const float* __restrict__ x, short* __restrict__ XP) {
  const int b = blockIdx.y;
  const int i0 = (blockIdx.x * 256 + threadIdx.x) * 8;
  if (i0 >= LPAD) return;
  const float* xb = x + (size_t)b * LSIG;
  const int j0 = i0 - 1024;
  short8 v;
  if (j0 >= 0 && j0 + 8 <= LSIG) {
    float4 a = *(const float4*)(xb + j0);
    float4 c = *(const float4*)(xb + j0 + 4);
    v = pack8(a, c);
  } else {
    #pragma unroll
    for (int e = 0; e < 8; ++e) {
      int j = j0 + e;
      j = j < 0 ? -j : (j >= LSIG ? 2 * LSIG - 2 - j : j);
      v[e] = bf16r(xb[j]);
    }
  }
  *(short8*)&XP[(size_t)b * LPAD + i0] = v;
}

// -------- stage 1b: basis f32 -> bf16, split real/imag, zero-pad rows --------
__global__ void convert_basis(const float* __restrict__ bs, short* __restrict__ A) {
  const int row = blockIdx.x;               // 0..2*MPAD-1
  const int p = row / MPAD;
  const int k = row - p * MPAD;
  const size_t dst = (size_t)row * FILT;
  const int i = threadIdx.x * 8;
  short8 v;
  if (k < CUT) {
    const float* src = bs + (size_t)(p * CUT + k) * FILT + i;
    float4 a = *(const float4*)src;
    float4 c = *(const float4*)(src + 4);
    v = pack8(a, c);
  } else {
    v = (short8)(short)0;
  }
  *(short8*)&A[dst + i] = v;
}

// -------- stage 2: fused GEMM + magnitude --------
__global__ __launch_bounds__(512, 2)
void stft_gemm8(const short* __restrict__ Aw, const short* __restrict__ XP,
                float* __restrict__ out)
{
  __shared__ alignas(16) short sA[2][256][64];   // [buf][plane*128+row][col] 64 KiB
  __shared__ alignas(16) short sB[2][256][64];   // [buf][frame row][col]     64 KiB

  const int tid  = threadIdx.x;
  const int wave = tid >> 6;
  const int lane = tid & 63;
  const int wr = wave >> 2;          // 0..1: 64-bin half
  const int wc = wave & 3;           // 0..3: 64-frame quarter

  // bijective XCD-aware block swizzle (m204)
  int bid = blockIdx.x;
  { const int q = NWG / 8, r = NWG % 8, xc = bid & 7, o = bid >> 3;
    bid = (xc < r ? xc * (q + 1) : r * (q + 1) + (xc - r) * q) + o; }
  const int by = bid / NT, bx = bid - by * NT;
  const int m0 = by * BM, n0 = bx * BN;

  // ---- staging geometry (pre-swizzled global source, linear LDS dest) ----
  const int lrow = lane >> 3;                 // row within 8-row chunk
  const int soff = ((lane & 7) ^ lrow) * 8;   // swizzled source col (shorts)
  const int ch0 = wave * 2, ch1 = wave * 2 + 1;

  // A sources: ws layout [2][MPAD][FILT]
  const short* aRow0 = Aw + (size_t)(m0 + ch0 * 8 + lrow) * FILT + soff;
  const short* aRow1 = Aw + (size_t)(m0 + ch1 * 8 + lrow) * FILT + soff;
  const size_t planeOff = (size_t)MPAD * FILT;

  // B sources: padded signal, frame f -> XP[b(f)] + t(f)*HOP, row stride HOP
  const short* bPtr[2][2];
  #pragma unroll
  for (int h = 0; h < 2; ++h) {
    #pragma unroll
    for (int c = 0; c < 2; ++c) {
      int f = n0 + h * 128 + (c ? ch1 : ch0) * 8 + lrow;
      if (f > NFR - 1) f = NFR - 1;
      const int bb = f / TFR, tt = f - bb * TFR;
      bPtr[h][c] = XP + (size_t)bb * LPAD + (size_t)tt * HOP + soff;
    }
  }

  auto stageA = [&](int p, int bf, int k0) {   // plane p (0=real,1=imag), 128 rows
    gld_lds16(aRow0 + (size_t)p * planeOff + k0, &sA[bf][p * 128 + ch0 * 8][0]);
    gld_lds16(aRow1 + (size_t)p * planeOff + k0, &sA[bf][p * 128 + ch1 * 8][0]);
  };
  auto stageB = [&](int h, int bf, int k0) {   // frame half h, 128 rows
    gld_lds16(bPtr[h][0] + k0, &sB[bf][h * 128 + ch0 * 8][0]);
    gld_lds16(bPtr[h][1] + k0, &sB[bf][h * 128 + ch1 * 8][0]);
  };

  // ---- frag-read geometry (swizzled ds_read; row&7 == lane&7 for all frags) ----
  const int fr = lane & 15;
  const int l7 = lane & 7;
  const int fg = lane >> 4;                       // 0..3
  const int g0 = (fg ^ l7) * 8;                   // k-half 0 granule (shorts)
  const int g1 = ((4 + fg) ^ l7) * 8;             // k-half 1

  f32x4 acc_r[4][4], acc_i[4][4];
  #pragma unroll
  for (int m = 0; m < 4; ++m)
    #pragma unroll
    for (int n = 0; n < 4; ++n) { acc_r[m][n] = (f32x4)0.f; acc_i[m][n] = (f32x4)0.f; }

  short8 ar[4], ai[4], b[4];

  auto rdAr = [&](int kh, int bf) {
    const int g = kh ? g1 : g0;
    #pragma unroll
    for (int m = 0; m < 4; ++m)
      ar[m] = *(const short8*)&sA[bf][wr * 64 + m * 16 + fr][g];
  };
  auto rdAi = [&](int kh, int bf) {
    const int g = kh ? g1 : g0;
    #pragma unroll
    for (int m = 0; m < 4; ++m)
      ai[m] = *(const short8*)&sA[bf][128 + wr * 64 + m * 16 + fr][g];
  };
  auto rdB = [&](int kh, int bf) {
    const int g = kh ? g1 : g0;
    #pragma unroll
    for (int n = 0; n < 4; ++n)
      b[n] = *(const short8*)&sB[bf][wc * 64 + n * 16 + fr][g];
  };

  auto MMr = [&]() {
    __builtin_amdgcn_s_setprio(1);
    #pragma unroll
    for (int m = 0; m < 4; ++m)
      #pragma unroll
      for (int n = 0; n < 4; ++n)
        acc_r[m][n] = __builtin_amdgcn_mfma_f32_16x16x32_bf16(ar[m], b[n], acc_r[m][n], 0, 0, 0);
    __builtin_amdgcn_s_setprio(0);
  };
  auto MMi = [&]() {
    __builtin_amdgcn_s_setprio(1);
    #pragma unroll
    for (int m = 0; m < 4; ++m)
      #pragma unroll
      for (int n = 0; n < 4; ++n)
        acc_i[m][n] = __builtin_amdgcn_mfma_f32_16x16x32_bf16(ai[m], b[n], acc_i[m][n], 0, 0, 0);
    __builtin_amdgcn_s_setprio(0);
  };

  // ---- prologue: stage tile 0 -> buf 0; gate B0,B1,A0; leave A1 in flight ----
  stageB(0, 0, 0);
  stageB(1, 0, 0);
  stageA(0, 0, 0);
  stageA(1, 0, 0);
  asm volatile("s_waitcnt vmcnt(2)" ::: "memory");
  barf();
  // invariant at loop top: outstanding = A1(t) only

  #pragma unroll 2
  for (int t = 0; t < NK; ++t) {
    const int b_ = t & 1, bn = b_ ^ 1;
    const int k1 = ((t + 1) & (NK - 1)) * BK;   // wraps on last iter (garbage, drained)

    // ph0: real x k-half0. Reads need B0,B1,A0(t): gated by prev ph3 / prologue.
    rdAr(0, b_); rdB(0, b_);
    stageB(0, bn, k1);
    stageB(1, bn, k1);
    stageA(0, bn, k1);
    asm volatile("s_waitcnt vmcnt(6)" ::: "memory");   // drain A1(t); 3-phase distance
    barf();
    MMr();
    barf();

    // ph1: imag x k-half0 (reuse b). Needs A1(t): gated by ph0's vmcnt.
    rdAi(0, b_);
    stageA(1, bn, k1);
    barf();
    MMi();
    barf();

    // ph2: real x k-half1. Tile t fully resident.
    rdAr(1, b_); rdB(1, b_);
    barf();
    MMr();
    barf();

    // ph3: imag x k-half1.
    rdAi(1, b_);
    asm volatile("s_waitcnt vmcnt(2)" ::: "memory");   // drain B0,B1,A0(t+1); 3-phase distance
    barf();
    MMi();
    barf();
  }
  asm volatile("s_waitcnt vmcnt(0)" ::: "memory");

  // ---- epilogue: magnitude, guarded strided write ----
  const int cl = lane & 15;
  const int rg = (lane >> 4) * 4;
  #pragma unroll
  for (int n = 0; n < 4; ++n) {
    const int f = n0 + wc * 64 + n * 16 + cl;
    if (f >= NFR) continue;
    const int bb = f / TFR, tt = f - bb * TFR;
    float* ob = out + (size_t)bb * (CUT * TFR) + tt;
    #pragma unroll
    for (int m = 0; m < 4; ++m) {
      #pragma unroll
      for (int r = 0; r < 4; ++r) {
        const int k = m0 + wr * 64 + m * 16 + rg + r;
        if (k < CUT) {
          float re = acc_r[m][n][r];
          float im = acc_i[m][n][r];
          ob[(size_t)k * TFR] = sqrtf(re * re + im * im);
        }
      }
    }
  }
}

// -------- fallback: reg-staged 128x128 (no ws needed) --------
__global__ __launch_bounds__(256, 2)
void stft_gemm_fb(const float* __restrict__ basis, const float* __restrict__ x,
                  float* __restrict__ out)
{
  __shared__ alignas(16) short sA[2][128][64];
  __shared__ alignas(16) short sB[128][64];

  const int tid  = threadIdx.x;
  const int wave = tid >> 6;
  const int lane = tid & 63;
  const int n0 = blockIdx.x * 128;
  const int m0 = blockIdx.y * 128;

  f32x4 acc_r[4][4], acc_i[4][4];
  #pragma unroll
  for (int i = 0; i < 4; ++i)
    #pragma unroll
    for (int j = 0; j < 4; ++j) { acc_r[i][j] = (f32x4)0.f; acc_i[i][j] = (f32x4)0.f; }

  const int sr = tid >> 1;
  const int sh = (tid & 1) * 32;

  for (int k0 = 0; k0 < FILT; k0 += BK) {
    #pragma unroll
    for (int p = 0; p < 2; ++p) {
      const int k = m0 + sr;
      short8 v[4];
      if (k < CUT) {
        const float* src = basis + (size_t)(p * CUT + k) * FILT + k0 + sh;
        #pragma unroll
        for (int q = 0; q < 4; ++q) {
          float4 a = *(const float4*)(src + q * 8);
          float4 b = *(const float4*)(src + q * 8 + 4);
          v[q] = pack8(a, b);
        }
      } else {
        #pragma unroll
        for (int q = 0; q < 4; ++q) v[q] = (short8)(short)0;
      }
      #pragma unroll
      for (int q = 0; q < 4; ++q) *(short8*)&sA[p][sr][sh + q * 8] = v[q];
    }
    {
      const int f = n0 + sr;
      short8 v[4];
      if (f < NFR) {
        const int b = f / TFR, t = f - b * TFR;
        const float* xb = x + (size_t)b * LSIG;
        const int j0 = t * HOP + k0 + sh - 1024;
        if (j0 >= 0 && j0 + 32 <= LSIG) {
          #pragma unroll
          for (int q = 0; q < 4; ++q) {
            float4 a  = *(const float4*)(xb + j0 + q * 8);
            float4 b2 = *(const float4*)(xb + j0 + q * 8 + 4);
            v[q] = pack8(a, b2);
          }
        } else {
          #pragma unroll
          for (int q = 0; q < 4; ++q)
            #pragma unroll
            for (int e = 0; e < 8; ++e) {
              int j = j0 + q * 8 + e;
              j = j < 0 ? -j : (j >= LSIG ? 2 * LSIG - 2 - j : j);
              v[q][e] = bf16r(xb[j]);
            }
        }
      } else {
        #pragma unroll
        for (int q = 0; q < 4; ++q) v[q] = (short8)(short)0;
      }
      #pragma unroll
      for (int q = 0; q < 4; ++q) *(short8*)&sB[sr][sh + q * 8] = v[q];
    }
    __syncthreads();

    const int ra = lane & 15;
    #pragma unroll
    for (int kk = 0; kk < BK; kk += 32) {
      const int col = kk + (lane >> 4) * 8;
      short8 arr[4], aii[4], bfr[4];
      #pragma unroll
      for (int i = 0; i < 4; ++i) {
        const int rm = (wave >> 1) * 64 + i * 16 + ra;
        arr[i] = *(const short8*)&sA[0][rm][col];
        aii[i] = *(const short8*)&sA[1][rm][col];
        const int rn = (wave & 1) * 64 + i * 16 + ra;
        bfr[i] = *(const short8*)&sB[rn][col];
      }
      #pragma unroll
      for (int i = 0; i < 4; ++i)
        #pragma unroll
        for (int j = 0; j < 4; ++j) {
          acc_r[i][j] = __builtin_amdgcn_mfma_f32_16x16x32_bf16(arr[i], bfr[j], acc_r[i][j], 0, 0, 0);
          acc_i[i][j] = __builtin_amdgcn_mfma_f32_16x16x32_bf16(aii[i], bfr[j], acc_i[i][j], 0, 0, 0);
        }
    }
    __syncthreads();
  }

  const int wm0 = m0 + (wave >> 1) * 64;
  const int wn0 = n0 + (wave & 1) * 64;
  const int cl = lane & 15;
  const int rg = (lane >> 4) * 4;
  #pragma unroll
  for (int j = 0; j < 4; ++j) {
    const int f = wn0 + j * 16 + cl;
    if (f >= NFR) continue;
    const int b = f / TFR, t = f - b * TFR;
    float* ob = out + (size_t)b * (CUT * TFR) + t;
    #pragma unroll
    for (int i = 0; i < 4; ++i) {
      #pragma unroll
      for (int r = 0; r < 4; ++r) {
        const int k = wm0 + i * 16 + rg + r;
        if (k < CUT) {
          float re = acc_r[i][j][r], im = acc_i[i][j][r];
          ob[(size_t)k * TFR] = sqrtf(re * re + im * im);
        }
      }
    }
  }
}

extern "C" void kernel_launch(void* const* d_in, const int* in_sizes, int n_in,
                              void* d_out, int out_size, void* d_ws, size_t ws_size,
                              hipStream_t stream) {
  const float* x     = (const float*)d_in[0];
  const float* basis = (const float*)d_in[1];
  float* out = (float*)d_out;

  const size_t sbytes = (size_t)NBATCH * LPAD * sizeof(short);     // 20,611,072
  const size_t abytes = (size_t)2 * MPAD * FILT * sizeof(short);   //  9,437,184

  if (ws_size >= sbytes + abytes) {
    short* XP = (short*)d_ws;
    short* A  = (short*)((char*)d_ws + sbytes);
    pad_signal<<<dim3((LPAD + 2047) / 2048, NBATCH), 256, 0, stream>>>(x, XP);
    convert_basis<<<2 * MPAD, 256, 0, stream>>>(basis, A);
    stft_gemm8<<<NWG, 512, 0, stream>>>(A, XP, out);
  } else {
    stft_gemm_fb<<<dim3(157, 9), 256, 0, stream>>>(basis, x, out);
  }
}